// Round 20
// baseline (239.588 us; speedup 1.0000x reference)
//
#include <hip/hip_runtime.h>

typedef _Float16 half8 __attribute__((ext_vector_type(8)));
typedef _Float16 half4v __attribute__((ext_vector_type(4)));
typedef __fp16 fp16x2 __attribute__((ext_vector_type(2)));
typedef float f32x4 __attribute__((ext_vector_type(4)));
typedef float f32x16 __attribute__((ext_vector_type(16)));
typedef unsigned uint2v __attribute__((ext_vector_type(2)));

__device__ __forceinline__ void gld_lds16(const void* g, void* l) {
  __builtin_amdgcn_global_load_lds((const __attribute__((address_space(1))) void*)g,
                                   (__attribute__((address_space(3))) void*)l, 16, 0, 0);
}

// raw v_exp_f32 (args in [-40,0]; avoids __ocml_exp2_f32 denormal-fixup libcall)
__device__ __forceinline__ float fexp2(float x) { return __builtin_amdgcn_exp2f(x); }

__device__ __forceinline__ unsigned pku(float a, float b) {
  union { fp16x2 p; unsigned u; } u;
  u.p = __builtin_amdgcn_cvt_pkrtz(a, b);
  return u.u;
}
__device__ __forceinline__ half4v pk4(float a, float b, float c, float d) {
  union { fp16x2 p[2]; half4v v; } u;
  u.p[0] = __builtin_amdgcn_cvt_pkrtz(a, b);
  u.p[1] = __builtin_amdgcn_cvt_pkrtz(c, d);
  return u.v;
}

// ---------------- fp32 -> f16 convert: x ----------------
__global__ void cvt_f32_f16(const float* __restrict__ src, _Float16* __restrict__ dst, int n4) {
  int i = blockIdx.x * 256 + threadIdx.x;
  if (i < n4) {
    float4 v = ((const float4*)src)[i];
    half4v h;
    h.x = (_Float16)v.x; h.y = (_Float16)v.y; h.z = (_Float16)v.z; h.w = (_Float16)v.w;
    ((half4v*)dst)[i] = h;
  }
}

// ---------------- fused weight convert: Wq,Wk,Wv -> packed Wqkv[3072][1024]; Wo -> Woh ---
__global__ void cvt_w4(const float* __restrict__ Wq, const float* __restrict__ Wk,
                       const float* __restrict__ Wv, const float* __restrict__ Wo,
                       _Float16* __restrict__ Wqkv, _Float16* __restrict__ Woh) {
  int i = blockIdx.x * 256 + threadIdx.x;   // float4 index over 4 x 262144
  int which = i >> 18;
  int local = i & 262143;
  const float* src = which == 0 ? Wq : which == 1 ? Wk : which == 2 ? Wv : Wo;
  float4 v = ((const float4*)src)[local];
  half4v h;
  h.x = (_Float16)v.x; h.y = (_Float16)v.y; h.z = (_Float16)v.z; h.w = (_Float16)v.w;
  _Float16* dst = which < 3 ? Wqkv + (size_t)which * 1048576 : Woh;
  ((half4v*)dst)[local] = h;
}

// ---------------- mask tile flags: flag=1 iff no zeros in 128x64 tile ----------------
__global__ void mask_flags_k(const int* __restrict__ mask, unsigned char* __restrict__ flags) {
  int qt = blockIdx.x, kt = blockIdx.y; // 16 x 32
  __shared__ int allv;
  if (threadIdx.x == 0) allv = 1;
  __syncthreads();
  int ok = 1;
  for (int idx = threadIdx.x; idx < 128 * 64; idx += 256) {
    int qr = qt * 128 + (idx >> 6);
    int kc = kt * 64 + (idx & 63);
    ok &= (mask[(size_t)qr * 2048 + kc] != 0);
  }
  if (!ok) atomicAnd(&allv, 0);
  __syncthreads();
  if (threadIdx.x == 0) flags[qt * 32 + kt] = (unsigned char)allv;
}

// stage one 128x32 f16 tile (8KB) from src row-major [.,1024] into DST
#define STAGE_TILE(DST, SRC, base0, kk0)                                         \
  _Pragma("unroll")                                                              \
  for (int cc = 0; cc < 2; ++cc) {                                               \
    int oo = w * 2048 + cc * 1024 + l * 16;                                      \
    int row_ = oo >> 6;                                                          \
    int kb_ = (oo & 63) >> 1;                                                    \
    gld_lds16(SRC + (size_t)((base0) + row_) * 1024 + (kk0) + kb_,               \
              (char*)&DST[0][0] + w * 2048 + cc * 1024);                         \
  }

// ds_read fragments + 16 MFMA on buffer BUFI
#define GEMM_COMPUTE(BUFI)                                                       \
  {                                                                              \
    half8 af[4], bf[4];                                                          \
    _Pragma("unroll")                                                            \
    for (int m = 0; m < 4; ++m) af[m] = *(const half8*)&Alds[BUFI][wm * 64 + m * 16 + lm][lg * 8]; \
    _Pragma("unroll")                                                            \
    for (int n = 0; n < 4; ++n) bf[n] = *(const half8*)&Blds[BUFI][wn * 64 + n * 16 + lm][lg * 8]; \
    __builtin_amdgcn_s_setprio(1);                                               \
    _Pragma("unroll")                                                            \
    for (int m = 0; m < 4; ++m)                                                  \
      _Pragma("unroll")                                                          \
      for (int n = 0; n < 4; ++n)                                                \
        acc[m][n] = __builtin_amdgcn_mfma_f32_16x16x32_f16(af[m], bf[n], acc[m][n], 0, 0, 0); \
    __builtin_amdgcn_s_setprio(0);                                               \
  }

// ---------------- fused QKV GEMM: y[8192,3072] = x @ Wqkv^T + bias (T4 schedule) ------
__global__ __launch_bounds__(256) void gemm_qkv(const _Float16* __restrict__ A,
                                                const _Float16* __restrict__ B,
                                                const float* __restrict__ bq,
                                                const float* __restrict__ bk,
                                                const float* __restrict__ bv,
                                                _Float16* __restrict__ Qw,
                                                _Float16* __restrict__ Kw,
                                                _Float16* __restrict__ Vtt,
                                                float qscale) {
  __shared__ _Float16 Alds[2][128][32];
  __shared__ _Float16 Blds[2][128][32];
  int tid = threadIdx.x, w = tid >> 6, l = tid & 63;
  int lm = l & 15, lg = l >> 4;
  int wm = w >> 1, wn = w & 1;
  int wg = blockIdx.y * 24 + blockIdx.x;   // 1536 blocks
  int xcd = wg & 7, j = wg >> 3;           // j in 0..191
  int panel = j >> 6, rem = j & 63;        // 3 n-panels of 8m x 8n
  int m0 = (xcd * 8 + (rem >> 3)) * 128;
  int n0 = (panel * 8 + (rem & 7)) * 128;
  f32x4 acc[4][4] = {};
  STAGE_TILE(Alds[0], A, m0, 0);
  STAGE_TILE(Blds[0], B, n0, 0);
  int buf = 0;
  for (int k0 = 0; k0 < 992; k0 += 32) {
    STAGE_TILE(Alds[buf ^ 1], A, m0, k0 + 32);
    STAGE_TILE(Blds[buf ^ 1], B, n0, k0 + 32);
    asm volatile("s_waitcnt vmcnt(4)" ::: "memory");
    __builtin_amdgcn_s_barrier();
    __builtin_amdgcn_sched_barrier(0);
    GEMM_COMPUTE(buf);
    __builtin_amdgcn_sched_barrier(0);
    __builtin_amdgcn_s_barrier();
    buf ^= 1;
  }
  asm volatile("s_waitcnt vmcnt(0)" ::: "memory");
  __builtin_amdgcn_s_barrier();
  __builtin_amdgcn_sched_barrier(0);
  GEMM_COMPUTE(buf);
  int which = n0 >> 10;                       // 0:Q 1:K 2:V (uniform per block)
  float osc = which == 0 ? qscale : 1.0f;
  const float* bias = which == 0 ? bq : which == 1 ? bk : bv;
  int cq0 = n0 & 1023;
  float bs[4];
#pragma unroll
  for (int n = 0; n < 4; ++n) bs[n] = bias[cq0 + wn * 64 + n * 16 + lm];
#pragma unroll
  for (int m = 0; m < 4; ++m) {
#pragma unroll
    for (int n = 0; n < 4; ++n) {
      int cq = cq0 + wn * 64 + n * 16 + lm;
      int hh = cq >> 6, d = cq & 63;
#pragma unroll
      for (int j2 = 0; j2 < 4; ++j2) {
        int rowg = m0 + wm * 64 + m * 16 + lg * 4 + j2;
        int b = rowg >> 11, s = rowg & 2047;
        float v = (acc[m][n][j2] + bs[n]) * osc;
        if (which == 2) {
          Vtt[((size_t)(b * 16 + hh) * 64 + d) * 2048 + s] = (_Float16)v;
        } else {
          _Float16* dst = which == 0 ? Qw : Kw;
          dst[((size_t)(b * 16 + hh) * 2048 + s) * 64 + d] = (_Float16)v;
        }
      }
    }
  }
}

// ---------------- output GEMM: y[8192,1024] = A @ Wo^T + bo (fp32 out), T4 schedule ---
__global__ __launch_bounds__(256) void gemm_o(const _Float16* __restrict__ A,
                                              const _Float16* __restrict__ B,
                                              const float* __restrict__ bias,
                                              float* __restrict__ dst) {
  __shared__ _Float16 Alds[2][128][32];
  __shared__ _Float16 Blds[2][128][32];
  int tid = threadIdx.x, w = tid >> 6, l = tid & 63;
  int lm = l & 15, lg = l >> 4;
  int wm = w >> 1, wn = w & 1;
  int wg = blockIdx.y * 8 + blockIdx.x;
  int xcd = wg & 7, j = wg >> 3;
  int m0 = (xcd * 8 + (j >> 3)) * 128, n0 = (j & 7) * 128;
  f32x4 acc[4][4] = {};
  STAGE_TILE(Alds[0], A, m0, 0);
  STAGE_TILE(Blds[0], B, n0, 0);
  int buf = 0;
  for (int k0 = 0; k0 < 992; k0 += 32) {
    STAGE_TILE(Alds[buf ^ 1], A, m0, k0 + 32);
    STAGE_TILE(Blds[buf ^ 1], B, n0, k0 + 32);
    asm volatile("s_waitcnt vmcnt(4)" ::: "memory");
    __builtin_amdgcn_s_barrier();
    __builtin_amdgcn_sched_barrier(0);
    GEMM_COMPUTE(buf);
    __builtin_amdgcn_sched_barrier(0);
    __builtin_amdgcn_s_barrier();
    buf ^= 1;
  }
  asm volatile("s_waitcnt vmcnt(0)" ::: "memory");
  __builtin_amdgcn_s_barrier();
  __builtin_amdgcn_sched_barrier(0);
  GEMM_COMPUTE(buf);
  float bs[4];
#pragma unroll
  for (int n = 0; n < 4; ++n) bs[n] = bias[n0 + wn * 64 + n * 16 + lm];
#pragma unroll
  for (int m = 0; m < 4; ++m)
#pragma unroll
    for (int n = 0; n < 4; ++n) {
      int colg = n0 + wn * 64 + n * 16 + lm;
#pragma unroll
      for (int j2 = 0; j2 < 4; ++j2) {
        int rowg = m0 + wm * 64 + m * 16 + lg * 4 + j2;
        dst[(size_t)rowg * 1024 + colg] = acc[m][n][j2] + bs[n];
      }
    }
}

// ---------------- flash attention ----------------
// ROUND 20: softmax denominator moved OFF the VALU pipe onto the MFMA pipe.
// acc2 = mfma(ones, P_frag, acc2): with A = all-ones, every C row equals the
// column-sum of P, i.e. Sigma_k P[q=c][k], accumulated across tiles by C-in.
// Deletes ~25 psum adds/tile from the 63%-busy VALU pipe (+4 MFMA on the 23%
// pipe) and the epilogue lrun shfl (acc2[0] is already the FULL row sum).
// Denominator now sums the same f16-rounded P the numerator uses. Defer-max
// rescale touches only acc2[0]. Everything else frozen from R19.
__global__ __launch_bounds__(256) void attn_k(const _Float16* __restrict__ Q,
                                              const _Float16* __restrict__ K,
                                              const _Float16* __restrict__ Vt,
                                              const unsigned char* __restrict__ flags,
                                              const int* __restrict__ mask,
                                              _Float16* __restrict__ out) {
  __shared__ __align__(16) char lds[2][16384];  // per buf: K tile 8KB, V tile 8KB
  int bh = blockIdx.x, qt = blockIdx.y;
  int tid = threadIdx.x, w = tid >> 6, l = tid & 63;
  int c = l & 31, h = l >> 5;
  const size_t hb = (size_t)bh * (2048 * 64);
  int q0 = qt * 128 + w * 32;
  const _Float16* Kb = K + hb;
  const _Float16* Vb = Vt + hb;
  const unsigned char* fl = flags + qt * 32;

  int sr = (l >> 3), scb = (l & 7) * 16;

  half8 qf[4];
#pragma unroll
  for (int ds = 0; ds < 4; ++ds)
    qf[ds] = *(const half8*)&Q[hb + (size_t)(q0 + c) * 64 + ds * 16 + h * 8];

  half8 ones8;
#pragma unroll
  for (int i = 0; i < 8; ++i) ones8[i] = (_Float16)1.0f;

  f32x16 oaccT[2] = {};
  f32x16 acc2 = {};       // denominator: every row = Sigma_k P[q=c][k]
  float mrun = -1e30f;

#pragma unroll
  for (int i = 0; i < 2; ++i) {
    int r = w * 16 + i * 8 + sr;
    int dk = (scb ^ ((r & 7) << 4)) >> 1;
    gld_lds16(Kb + (size_t)r * 64 + dk, &lds[0][(w * 16 + i * 8) * 128]);
    gld_lds16(Vb + (size_t)r * 2048 + dk, &lds[0][8192 + (w * 16 + i * 8) * 128]);
  }
  __syncthreads();
  int buf = 0;

  for (int t = 0; t < 32; ++t) {
    if (t < 31) {
#pragma unroll
      for (int i = 0; i < 2; ++i) {
        int r = w * 16 + i * 8 + sr;
        int dk = (scb ^ ((r & 7) << 4)) >> 1;
        gld_lds16(Kb + (size_t)((t + 1) * 64 + r) * 64 + dk,
                  &lds[buf ^ 1][(w * 16 + i * 8) * 128]);
        gld_lds16(Vb + (size_t)r * 2048 + (t + 1) * 64 + dk,
                  &lds[buf ^ 1][8192 + (w * 16 + i * 8) * 128]);
      }
    }
    int flg = fl[t];
    f32x16 sT[2];
    f32x16 z = {};
    __builtin_amdgcn_s_setprio(1);
#pragma unroll
    for (int n = 0; n < 2; ++n) {
      int kr = n * 32 + c;
#pragma unroll
      for (int ds = 0; ds < 4; ++ds) {
        half8 kf = *(const half8*)&lds[buf][kr * 128 + ((ds * 32 + h * 16) ^ ((kr & 7) << 4))];
        sT[n] = ds == 0 ? __builtin_amdgcn_mfma_f32_32x32x16_f16(kf, qf[0], z, 0, 0, 0)
                        : __builtin_amdgcn_mfma_f32_32x32x16_f16(kf, qf[ds], sT[n], 0, 0, 0);
      }
    }
    __builtin_amdgcn_s_setprio(0);
    if (!flg) {
#pragma unroll
      for (int n = 0; n < 2; ++n)
#pragma unroll
        for (int r = 0; r < 16; ++r) {
          int kc = t * 64 + n * 32 + (r & 3) + 8 * (r >> 2) + 4 * h;
          if (mask[(size_t)(q0 + c) * 2048 + kc] == 0) sT[n][r] = -1e30f;
        }
    }
    float mx[16];
#pragma unroll
    for (int r = 0; r < 16; ++r) mx[r] = fmaxf(sT[0][r], sT[1][r]);
#pragma unroll
    for (int step = 8; step >= 1; step >>= 1)
#pragma unroll
      for (int r = 0; r < 8; ++r)
        if (r < step) mx[r] = fmaxf(mx[r], mx[r + step]);
    float pmax = mx[0];
    pmax = fmaxf(pmax, __shfl_xor(pmax, 32, 64));
    if (!__all(pmax - mrun <= 8.f)) {
      float mnew = fmaxf(mrun, pmax);
      float alpha = fexp2(mrun - mnew);
#pragma unroll
      for (int dh = 0; dh < 2; ++dh)
#pragma unroll
        for (int r = 0; r < 16; ++r) oaccT[dh][r] *= alpha;
      acc2[0] *= alpha;     // only reg 0 is ever read
      mrun = mnew;
    }
    unsigned pk_[2][8];
#pragma unroll
    for (int n = 0; n < 2; ++n)
#pragma unroll
      for (int g = 0; g < 4; ++g) {
        float p0 = fexp2(sT[n][4 * g + 0] - mrun);
        float p1 = fexp2(sT[n][4 * g + 1] - mrun);
        float p2 = fexp2(sT[n][4 * g + 2] - mrun);
        float p3 = fexp2(sT[n][4 * g + 3] - mrun);
        pk_[n][2 * g] = pku(p0, p1);
        pk_[n][2 * g + 1] = pku(p2, p3);
      }
    __builtin_amdgcn_s_setprio(1);
#pragma unroll
    for (int n = 0; n < 2; ++n)
#pragma unroll
      for (int sp = 0; sp < 2; ++sp) {
        // T12: one permlane32_swap yields both output words
        uint2v r0 = __builtin_amdgcn_permlane32_swap(pk_[n][4 * sp + 0], pk_[n][4 * sp + 2], false, false);
        uint2v r1 = __builtin_amdgcn_permlane32_swap(pk_[n][4 * sp + 1], pk_[n][4 * sp + 3], false, false);
        union { unsigned u[4]; half8 v; } pb;
        pb.u[0] = r0[0];
        pb.u[1] = r1[0];
        pb.u[2] = r0[1];
        pb.u[3] = r1[1];
        int s = n * 2 + sp;
#pragma unroll
        for (int dh = 0; dh < 2; ++dh) {
          int vr = dh * 32 + c;
          half8 vfr = *(const half8*)&lds[buf][8192 + vr * 128 + ((s * 32 + h * 16) ^ ((vr & 7) << 4))];
          oaccT[dh] = __builtin_amdgcn_mfma_f32_32x32x16_f16(vfr, pb.v, oaccT[dh], 0, 0, 0);
        }
        // denominator on the MFMA pipe: rows of acc2 = column sums of P
        acc2 = __builtin_amdgcn_mfma_f32_32x32x16_f16(ones8, pb.v, acc2, 0, 0, 0);
      }
    __builtin_amdgcn_s_setprio(0);
    __syncthreads();
    buf ^= 1;
  }
  char* Pl = &lds[0][w * 4096];
  int bb = bh >> 4, hh = bh & 15;
  float rinv = 1.0f / acc2[0];   // full row sum (ones-row MFMA), no shfl needed
#pragma unroll
  for (int dh = 0; dh < 2; ++dh)
#pragma unroll
    for (int g = 0; g < 4; ++g) {
      int dbase = dh * 32 + 8 * g + 4 * h;
      int byte = c * 128 + ((dbase * 2) ^ ((c & 7) << 4));
      *(half4v*)(&Pl[byte]) = pk4(oaccT[dh][4 * g + 0] * rinv, oaccT[dh][4 * g + 1] * rinv,
                                  oaccT[dh][4 * g + 2] * rinv, oaccT[dh][4 * g + 3] * rinv);
    }
#pragma unroll
  for (int r = 0; r < 4; ++r) {
    int o = r * 1024 + l * 16;
    int row = o >> 7;
    int pb_ = o & 127;
    int d2 = pb_ ^ ((row & 7) << 4);
    half8 v = *(const half8*)&Pl[row * 128 + pb_];
    *(half8*)&out[((size_t)(bb * 2048 + q0 + row)) * 1024 + hh * 64 + (d2 >> 1)] = v;
  }
}

extern "C" void kernel_launch(void* const* d_in, const int* in_sizes, int n_in,
                              void* d_out, int out_size, void* d_ws, size_t ws_size,
                              hipStream_t stream) {
  const float* x = (const float*)d_in[0];
  const int* mask = (const int*)d_in[1];
  const float* Wq = (const float*)d_in[2];
  const float* bq = (const float*)d_in[3];
  const float* Wk = (const float*)d_in[4];
  const float* bk = (const float*)d_in[5];
  const float* Wv = (const float*)d_in[6];
  const float* bv = (const float*)d_in[7];
  const float* Wo = (const float*)d_in[8];
  const float* bo = (const float*)d_in[9];

  char* ws = (char*)d_ws;
  _Float16* xh = (_Float16*)(ws);                       // 16 MB, later reused as attn out
  _Float16* Wqkvh = (_Float16*)(ws + (16ull << 20));    // 6 MB packed [3072][1024]
  _Float16* Woh = (_Float16*)(ws + (22ull << 20));      // 2 MB
  _Float16* Vt = (_Float16*)(ws + (24ull << 20));       // 16 MB
  unsigned char* flags = (unsigned char*)(ws + (40ull << 20));  // 512 B
  // Q and K scratch live inside d_out (32 MB fp32), fully overwritten by final GEMM
  _Float16* Qw = (_Float16*)d_out;
  _Float16* Kw = (_Float16*)((char*)d_out + (16ull << 20));
  _Float16* Ah = xh;  // attention output reuses x-f16 region

  const float QSCALE = 0.125f * 1.4426950408889634f;  // 1/sqrt(64) * log2(e)

  cvt_f32_f16<<<8192, 256, 0, stream>>>(x, xh, 2097152);
  cvt_w4<<<4096, 256, 0, stream>>>(Wq, Wk, Wv, Wo, Wqkvh, Woh);
  mask_flags_k<<<dim3(16, 32), 256, 0, stream>>>(mask, flags);
  gemm_qkv<<<dim3(24, 64), 256, 0, stream>>>(xh, Wqkvh, bq, bk, bv, Qw, Kw, Vt, QSCALE);
  attn_k<<<dim3(64, 16), 256, 0, stream>>>(Qw, Kw, Vt, flags, mask, Ah);
  gemm_o<<<dim3(8, 64), 256, 0, stream>>>(Ah, Woh, bo, (float*)d_out);
}

// Round 21
// 232.980 us; speedup vs baseline: 1.0284x; 1.0284x over previous
//
#include <hip/hip_runtime.h>

typedef _Float16 half8 __attribute__((ext_vector_type(8)));
typedef _Float16 half4v __attribute__((ext_vector_type(4)));
typedef __fp16 fp16x2 __attribute__((ext_vector_type(2)));
typedef float f32x4 __attribute__((ext_vector_type(4)));
typedef float f32x16 __attribute__((ext_vector_type(16)));
typedef unsigned uint2v __attribute__((ext_vector_type(2)));

__device__ __forceinline__ void gld_lds16(const void* g, void* l) {
  __builtin_amdgcn_global_load_lds((const __attribute__((address_space(1))) void*)g,
                                   (__attribute__((address_space(3))) void*)l, 16, 0, 0);
}

// raw v_exp_f32 (args in [-40,0]; avoids __ocml_exp2_f32 denormal-fixup libcall)
__device__ __forceinline__ float fexp2(float x) { return __builtin_amdgcn_exp2f(x); }

__device__ __forceinline__ unsigned pku(float a, float b) {
  union { fp16x2 p; unsigned u; } u;
  u.p = __builtin_amdgcn_cvt_pkrtz(a, b);
  return u.u;
}
__device__ __forceinline__ half4v pk4(float a, float b, float c, float d) {
  union { fp16x2 p[2]; half4v v; } u;
  u.p[0] = __builtin_amdgcn_cvt_pkrtz(a, b);
  u.p[1] = __builtin_amdgcn_cvt_pkrtz(c, d);
  return u.v;
}

// ---------------- fp32 -> f16 convert: x ----------------
__global__ void cvt_f32_f16(const float* __restrict__ src, _Float16* __restrict__ dst, int n4) {
  int i = blockIdx.x * 256 + threadIdx.x;
  if (i < n4) {
    float4 v = ((const float4*)src)[i];
    half4v h;
    h.x = (_Float16)v.x; h.y = (_Float16)v.y; h.z = (_Float16)v.z; h.w = (_Float16)v.w;
    ((half4v*)dst)[i] = h;
  }
}

// ---------------- fused weight convert: Wq,Wk,Wv -> packed Wqkv[3072][1024]; Wo -> Woh ---
__global__ void cvt_w4(const float* __restrict__ Wq, const float* __restrict__ Wk,
                       const float* __restrict__ Wv, const float* __restrict__ Wo,
                       _Float16* __restrict__ Wqkv, _Float16* __restrict__ Woh) {
  int i = blockIdx.x * 256 + threadIdx.x;   // float4 index over 4 x 262144
  int which = i >> 18;
  int local = i & 262143;
  const float* src = which == 0 ? Wq : which == 1 ? Wk : which == 2 ? Wv : Wo;
  float4 v = ((const float4*)src)[local];
  half4v h;
  h.x = (_Float16)v.x; h.y = (_Float16)v.y; h.z = (_Float16)v.z; h.w = (_Float16)v.w;
  _Float16* dst = which < 3 ? Wqkv + (size_t)which * 1048576 : Woh;
  ((half4v*)dst)[local] = h;
}

// ---------------- mask tile flags: flag=1 iff no zeros in 128x64 tile ----------------
__global__ void mask_flags_k(const int* __restrict__ mask, unsigned char* __restrict__ flags) {
  int qt = blockIdx.x, kt = blockIdx.y; // 16 x 32
  __shared__ int allv;
  if (threadIdx.x == 0) allv = 1;
  __syncthreads();
  int ok = 1;
  for (int idx = threadIdx.x; idx < 128 * 64; idx += 256) {
    int qr = qt * 128 + (idx >> 6);
    int kc = kt * 64 + (idx & 63);
    ok &= (mask[(size_t)qr * 2048 + kc] != 0);
  }
  if (!ok) atomicAnd(&allv, 0);
  __syncthreads();
  if (threadIdx.x == 0) flags[qt * 32 + kt] = (unsigned char)allv;
}

// stage one 128x32 f16 tile (8KB) from src row-major [.,1024] into DST
#define STAGE_TILE(DST, SRC, base0, kk0)                                         \
  _Pragma("unroll")                                                              \
  for (int cc = 0; cc < 2; ++cc) {                                               \
    int oo = w * 2048 + cc * 1024 + l * 16;                                      \
    int row_ = oo >> 6;                                                          \
    int kb_ = (oo & 63) >> 1;                                                    \
    gld_lds16(SRC + (size_t)((base0) + row_) * 1024 + (kk0) + kb_,               \
              (char*)&DST[0][0] + w * 2048 + cc * 1024);                         \
  }

// ds_read fragments + 16 MFMA on buffer BUFI
#define GEMM_COMPUTE(BUFI)                                                       \
  {                                                                              \
    half8 af[4], bf[4];                                                          \
    _Pragma("unroll")                                                            \
    for (int m = 0; m < 4; ++m) af[m] = *(const half8*)&Alds[BUFI][wm * 64 + m * 16 + lm][lg * 8]; \
    _Pragma("unroll")                                                            \
    for (int n = 0; n < 4; ++n) bf[n] = *(const half8*)&Blds[BUFI][wn * 64 + n * 16 + lm][lg * 8]; \
    __builtin_amdgcn_s_setprio(1);                                               \
    _Pragma("unroll")                                                            \
    for (int m = 0; m < 4; ++m)                                                  \
      _Pragma("unroll")                                                          \
      for (int n = 0; n < 4; ++n)                                                \
        acc[m][n] = __builtin_amdgcn_mfma_f32_16x16x32_f16(af[m], bf[n], acc[m][n], 0, 0, 0); \
    __builtin_amdgcn_s_setprio(0);                                               \
  }

// ---------------- fused QKV GEMM: y[8192,3072] = x @ Wqkv^T + bias (T4 schedule) ------
__global__ __launch_bounds__(256) void gemm_qkv(const _Float16* __restrict__ A,
                                                const _Float16* __restrict__ B,
                                                const float* __restrict__ bq,
                                                const float* __restrict__ bk,
                                                const float* __restrict__ bv,
                                                _Float16* __restrict__ Qw,
                                                _Float16* __restrict__ Kw,
                                                _Float16* __restrict__ Vtt,
                                                float qscale) {
  __shared__ _Float16 Alds[2][128][32];
  __shared__ _Float16 Blds[2][128][32];
  int tid = threadIdx.x, w = tid >> 6, l = tid & 63;
  int lm = l & 15, lg = l >> 4;
  int wm = w >> 1, wn = w & 1;
  int wg = blockIdx.y * 24 + blockIdx.x;   // 1536 blocks
  int xcd = wg & 7, j = wg >> 3;           // j in 0..191
  int panel = j >> 6, rem = j & 63;        // 3 n-panels of 8m x 8n
  int m0 = (xcd * 8 + (rem >> 3)) * 128;
  int n0 = (panel * 8 + (rem & 7)) * 128;
  f32x4 acc[4][4] = {};
  STAGE_TILE(Alds[0], A, m0, 0);
  STAGE_TILE(Blds[0], B, n0, 0);
  int buf = 0;
  for (int k0 = 0; k0 < 992; k0 += 32) {
    STAGE_TILE(Alds[buf ^ 1], A, m0, k0 + 32);
    STAGE_TILE(Blds[buf ^ 1], B, n0, k0 + 32);
    asm volatile("s_waitcnt vmcnt(4)" ::: "memory");
    __builtin_amdgcn_s_barrier();
    __builtin_amdgcn_sched_barrier(0);
    GEMM_COMPUTE(buf);
    __builtin_amdgcn_sched_barrier(0);
    __builtin_amdgcn_s_barrier();
    buf ^= 1;
  }
  asm volatile("s_waitcnt vmcnt(0)" ::: "memory");
  __builtin_amdgcn_s_barrier();
  __builtin_amdgcn_sched_barrier(0);
  GEMM_COMPUTE(buf);
  int which = n0 >> 10;                       // 0:Q 1:K 2:V (uniform per block)
  float osc = which == 0 ? qscale : 1.0f;
  const float* bias = which == 0 ? bq : which == 1 ? bk : bv;
  int cq0 = n0 & 1023;
  float bs[4];
#pragma unroll
  for (int n = 0; n < 4; ++n) bs[n] = bias[cq0 + wn * 64 + n * 16 + lm];
#pragma unroll
  for (int m = 0; m < 4; ++m) {
#pragma unroll
    for (int n = 0; n < 4; ++n) {
      int cq = cq0 + wn * 64 + n * 16 + lm;
      int hh = cq >> 6, d = cq & 63;
#pragma unroll
      for (int j2 = 0; j2 < 4; ++j2) {
        int rowg = m0 + wm * 64 + m * 16 + lg * 4 + j2;
        int b = rowg >> 11, s = rowg & 2047;
        float v = (acc[m][n][j2] + bs[n]) * osc;
        if (which == 2) {
          Vtt[((size_t)(b * 16 + hh) * 64 + d) * 2048 + s] = (_Float16)v;
        } else {
          _Float16* dst = which == 0 ? Qw : Kw;
          dst[((size_t)(b * 16 + hh) * 2048 + s) * 64 + d] = (_Float16)v;
        }
      }
    }
  }
}

// ---------------- output GEMM: y[8192,1024] = A @ Wo^T + bo (fp32 out), T4 schedule ---
__global__ __launch_bounds__(256) void gemm_o(const _Float16* __restrict__ A,
                                              const _Float16* __restrict__ B,
                                              const float* __restrict__ bias,
                                              float* __restrict__ dst) {
  __shared__ _Float16 Alds[2][128][32];
  __shared__ _Float16 Blds[2][128][32];
  int tid = threadIdx.x, w = tid >> 6, l = tid & 63;
  int lm = l & 15, lg = l >> 4;
  int wm = w >> 1, wn = w & 1;
  int wg = blockIdx.y * 8 + blockIdx.x;
  int xcd = wg & 7, j = wg >> 3;
  int m0 = (xcd * 8 + (j >> 3)) * 128, n0 = (j & 7) * 128;
  f32x4 acc[4][4] = {};
  STAGE_TILE(Alds[0], A, m0, 0);
  STAGE_TILE(Blds[0], B, n0, 0);
  int buf = 0;
  for (int k0 = 0; k0 < 992; k0 += 32) {
    STAGE_TILE(Alds[buf ^ 1], A, m0, k0 + 32);
    STAGE_TILE(Blds[buf ^ 1], B, n0, k0 + 32);
    asm volatile("s_waitcnt vmcnt(4)" ::: "memory");
    __builtin_amdgcn_s_barrier();
    __builtin_amdgcn_sched_barrier(0);
    GEMM_COMPUTE(buf);
    __builtin_amdgcn_sched_barrier(0);
    __builtin_amdgcn_s_barrier();
    buf ^= 1;
  }
  asm volatile("s_waitcnt vmcnt(0)" ::: "memory");
  __builtin_amdgcn_s_barrier();
  __builtin_amdgcn_sched_barrier(0);
  GEMM_COMPUTE(buf);
  float bs[4];
#pragma unroll
  for (int n = 0; n < 4; ++n) bs[n] = bias[n0 + wn * 64 + n * 16 + lm];
#pragma unroll
  for (int m = 0; m < 4; ++m)
#pragma unroll
    for (int n = 0; n < 4; ++n) {
      int colg = n0 + wn * 64 + n * 16 + lm;
#pragma unroll
      for (int j2 = 0; j2 < 4; ++j2) {
        int rowg = m0 + wm * 64 + m * 16 + lg * 4 + j2;
        dst[(size_t)rowg * 1024 + colg] = acc[m][n][j2] + bs[n];
      }
    }
}

// ---------------- flash attention ----------------
// ROUND 21: revert R20's neutral ones-MFMA (reclaim 24 VGPR, back to best-measured
// R19 config) + two serial-chain micro-opts:
//  - pmax cross-half reduce via permlane32_swap (VALU) instead of shfl_xor (DS pipe)
//  - max tree nested for v_max3 fusion (T17): ~31 -> ~20 fused ops per tile
__global__ __launch_bounds__(256) void attn_k(const _Float16* __restrict__ Q,
                                              const _Float16* __restrict__ K,
                                              const _Float16* __restrict__ Vt,
                                              const unsigned char* __restrict__ flags,
                                              const int* __restrict__ mask,
                                              _Float16* __restrict__ out) {
  __shared__ __align__(16) char lds[2][16384];  // per buf: K tile 8KB, V tile 8KB
  int bh = blockIdx.x, qt = blockIdx.y;
  int tid = threadIdx.x, w = tid >> 6, l = tid & 63;
  int c = l & 31, h = l >> 5;
  const size_t hb = (size_t)bh * (2048 * 64);
  int q0 = qt * 128 + w * 32;
  const _Float16* Kb = K + hb;
  const _Float16* Vb = Vt + hb;
  const unsigned char* fl = flags + qt * 32;

  int sr = (l >> 3), scb = (l & 7) * 16;

  half8 qf[4];
#pragma unroll
  for (int ds = 0; ds < 4; ++ds)
    qf[ds] = *(const half8*)&Q[hb + (size_t)(q0 + c) * 64 + ds * 16 + h * 8];

  f32x16 oaccT[2] = {};
  float mrun = -1e30f;
  float lrun = 0.f;

#pragma unroll
  for (int i = 0; i < 2; ++i) {
    int r = w * 16 + i * 8 + sr;
    int dk = (scb ^ ((r & 7) << 4)) >> 1;
    gld_lds16(Kb + (size_t)r * 64 + dk, &lds[0][(w * 16 + i * 8) * 128]);
    gld_lds16(Vb + (size_t)r * 2048 + dk, &lds[0][8192 + (w * 16 + i * 8) * 128]);
  }
  __syncthreads();
  int buf = 0;

  for (int t = 0; t < 32; ++t) {
    if (t < 31) {
#pragma unroll
      for (int i = 0; i < 2; ++i) {
        int r = w * 16 + i * 8 + sr;
        int dk = (scb ^ ((r & 7) << 4)) >> 1;
        gld_lds16(Kb + (size_t)((t + 1) * 64 + r) * 64 + dk,
                  &lds[buf ^ 1][(w * 16 + i * 8) * 128]);
        gld_lds16(Vb + (size_t)r * 2048 + (t + 1) * 64 + dk,
                  &lds[buf ^ 1][8192 + (w * 16 + i * 8) * 128]);
      }
    }
    int flg = fl[t];
    f32x16 sT[2];
    f32x16 z = {};
    __builtin_amdgcn_s_setprio(1);
#pragma unroll
    for (int n = 0; n < 2; ++n) {
      int kr = n * 32 + c;
#pragma unroll
      for (int ds = 0; ds < 4; ++ds) {
        half8 kf = *(const half8*)&lds[buf][kr * 128 + ((ds * 32 + h * 16) ^ ((kr & 7) << 4))];
        sT[n] = ds == 0 ? __builtin_amdgcn_mfma_f32_32x32x16_f16(kf, qf[0], z, 0, 0, 0)
                        : __builtin_amdgcn_mfma_f32_32x32x16_f16(kf, qf[ds], sT[n], 0, 0, 0);
      }
    }
    __builtin_amdgcn_s_setprio(0);
    if (!flg) {
#pragma unroll
      for (int n = 0; n < 2; ++n)
#pragma unroll
        for (int r = 0; r < 16; ++r) {
          int kc = t * 64 + n * 32 + (r & 3) + 8 * (r >> 2) + 4 * h;
          if (mask[(size_t)(q0 + c) * 2048 + kc] == 0) sT[n][r] = -1e30f;
        }
    }
    // ---- row max: v_max3-friendly nesting (T17), then permlane cross-half ----
    float m8[8];
#pragma unroll
    for (int r = 0; r < 8; ++r)
      m8[r] = fmaxf(fmaxf(fmaxf(sT[0][r], sT[0][r + 8]), sT[1][r]), sT[1][r + 8]);
    float pmax = fmaxf(fmaxf(fmaxf(m8[0], m8[1]), m8[2]),
                       fmaxf(fmaxf(fmaxf(m8[3], m8[4]), m8[5]), fmaxf(m8[6], m8[7])));
    {
      uint2v pr = __builtin_amdgcn_permlane32_swap(__float_as_uint(pmax), __float_as_uint(pmax),
                                                   false, false);
      pmax = fmaxf(__uint_as_float(pr[0]), __uint_as_float(pr[1]));
    }
    if (!__all(pmax - mrun <= 8.f)) {
      float mnew = fmaxf(mrun, pmax);
      float alpha = fexp2(mrun - mnew);
#pragma unroll
      for (int dh = 0; dh < 2; ++dh)
#pragma unroll
        for (int r = 0; r < 16; ++r) oaccT[dh][r] *= alpha;
      lrun *= alpha;
      mrun = mnew;
    }
    unsigned pk_[2][8];
    float psum = 0.f;
#pragma unroll
    for (int n = 0; n < 2; ++n)
#pragma unroll
      for (int g = 0; g < 4; ++g) {
        float p0 = fexp2(sT[n][4 * g + 0] - mrun);
        float p1 = fexp2(sT[n][4 * g + 1] - mrun);
        float p2 = fexp2(sT[n][4 * g + 2] - mrun);
        float p3 = fexp2(sT[n][4 * g + 3] - mrun);
        psum += (p0 + p1) + (p2 + p3);
        pk_[n][2 * g] = pku(p0, p1);
        pk_[n][2 * g + 1] = pku(p2, p3);
      }
    lrun += psum;
    __builtin_amdgcn_s_setprio(1);
#pragma unroll
    for (int n = 0; n < 2; ++n)
#pragma unroll
      for (int sp = 0; sp < 2; ++sp) {
        // T12: one permlane32_swap yields both output words
        uint2v r0 = __builtin_amdgcn_permlane32_swap(pk_[n][4 * sp + 0], pk_[n][4 * sp + 2], false, false);
        uint2v r1 = __builtin_amdgcn_permlane32_swap(pk_[n][4 * sp + 1], pk_[n][4 * sp + 3], false, false);
        union { unsigned u[4]; half8 v; } pb;
        pb.u[0] = r0[0];
        pb.u[1] = r1[0];
        pb.u[2] = r0[1];
        pb.u[3] = r1[1];
        int s = n * 2 + sp;
#pragma unroll
        for (int dh = 0; dh < 2; ++dh) {
          int vr = dh * 32 + c;
          half8 vfr = *(const half8*)&lds[buf][8192 + vr * 128 + ((s * 32 + h * 16) ^ ((vr & 7) << 4))];
          oaccT[dh] = __builtin_amdgcn_mfma_f32_32x32x16_f16(vfr, pb.v, oaccT[dh], 0, 0, 0);
        }
      }
    __builtin_amdgcn_s_setprio(0);
    __syncthreads();
    buf ^= 1;
  }
  char* Pl = &lds[0][w * 4096];
  int bb = bh >> 4, hh = bh & 15;
  float lsum = lrun + __shfl_xor(lrun, 32, 64);
  float rinv = 1.0f / lsum;
#pragma unroll
  for (int dh = 0; dh < 2; ++dh)
#pragma unroll
    for (int g = 0; g < 4; ++g) {
      int dbase = dh * 32 + 8 * g + 4 * h;
      int byte = c * 128 + ((dbase * 2) ^ ((c & 7) << 4));
      *(half4v*)(&Pl[byte]) = pk4(oaccT[dh][4 * g + 0] * rinv, oaccT[dh][4 * g + 1] * rinv,
                                  oaccT[dh][4 * g + 2] * rinv, oaccT[dh][4 * g + 3] * rinv);
    }
#pragma unroll
  for (int r = 0; r < 4; ++r) {
    int o = r * 1024 + l * 16;
    int row = o >> 7;
    int pb_ = o & 127;
    int d2 = pb_ ^ ((row & 7) << 4);
    half8 v = *(const half8*)&Pl[row * 128 + pb_];
    *(half8*)&out[((size_t)(bb * 2048 + q0 + row)) * 1024 + hh * 64 + (d2 >> 1)] = v;
  }
}

extern "C" void kernel_launch(void* const* d_in, const int* in_sizes, int n_in,
                              void* d_out, int out_size, void* d_ws, size_t ws_size,
                              hipStream_t stream) {
  const float* x = (const float*)d_in[0];
  const int* mask = (const int*)d_in[1];
  const float* Wq = (const float*)d_in[2];
  const float* bq = (const float*)d_in[3];
  const float* Wk = (const float*)d_in[4];
  const float* bk = (const float*)d_in[5];
  const float* Wv = (const float*)d_in[6];
  const float* bv = (const float*)d_in[7];
  const float* Wo = (const float*)d_in[8];
  const float* bo = (const float*)d_in[9];

  char* ws = (char*)d_ws;
  _Float16* xh = (_Float16*)(ws);                       // 16 MB, later reused as attn out
  _Float16* Wqkvh = (_Float16*)(ws + (16ull << 20));    // 6 MB packed [3072][1024]
  _Float16* Woh = (_Float16*)(ws + (22ull << 20));      // 2 MB
  _Float16* Vt = (_Float16*)(ws + (24ull << 20));       // 16 MB
  unsigned char* flags = (unsigned char*)(ws + (40ull << 20));  // 512 B
  // Q and K scratch live inside d_out (32 MB fp32), fully overwritten by final GEMM
  _Float16* Qw = (_Float16*)d_out;
  _Float16* Kw = (_Float16*)((char*)d_out + (16ull << 20));
  _Float16* Ah = xh;  // attention output reuses x-f16 region

  const float QSCALE = 0.125f * 1.4426950408889634f;  // 1/sqrt(64) * log2(e)

  cvt_f32_f16<<<8192, 256, 0, stream>>>(x, xh, 2097152);
  cvt_w4<<<4096, 256, 0, stream>>>(Wq, Wk, Wv, Wo, Wqkvh, Woh);
  mask_flags_k<<<dim3(16, 32), 256, 0, stream>>>(mask, flags);
  gemm_qkv<<<dim3(24, 64), 256, 0, stream>>>(xh, Wqkvh, bq, bk, bv, Qw, Kw, Vt, QSCALE);
  attn_k<<<dim3(64, 16), 256, 0, stream>>>(Qw, Kw, Vt, flags, mask, Ah);
  gemm_o<<<dim3(8, 64), 256, 0, stream>>>(Ah, Woh, bo, (float*)d_out);
}

// Round 22
// 229.012 us; speedup vs baseline: 1.0462x; 1.0173x over previous
//
#include <hip/hip_runtime.h>

typedef _Float16 half8 __attribute__((ext_vector_type(8)));
typedef _Float16 half4v __attribute__((ext_vector_type(4)));
typedef __fp16 fp16x2 __attribute__((ext_vector_type(2)));
typedef float f32x4 __attribute__((ext_vector_type(4)));
typedef float f32x16 __attribute__((ext_vector_type(16)));
typedef unsigned uint2v __attribute__((ext_vector_type(2)));

__device__ __forceinline__ void gld_lds16(const void* g, void* l) {
  __builtin_amdgcn_global_load_lds((const __attribute__((address_space(1))) void*)g,
                                   (__attribute__((address_space(3))) void*)l, 16, 0, 0);
}

// raw v_exp_f32 (args in [-40,0]; avoids __ocml_exp2_f32 denormal-fixup libcall)
__device__ __forceinline__ float fexp2(float x) { return __builtin_amdgcn_exp2f(x); }

__device__ __forceinline__ unsigned pku(float a, float b) {
  union { fp16x2 p; unsigned u; } u;
  u.p = __builtin_amdgcn_cvt_pkrtz(a, b);
  return u.u;
}
__device__ __forceinline__ half4v pk4(float a, float b, float c, float d) {
  union { fp16x2 p[2]; half4v v; } u;
  u.p[0] = __builtin_amdgcn_cvt_pkrtz(a, b);
  u.p[1] = __builtin_amdgcn_cvt_pkrtz(c, d);
  return u.v;
}

// ---------------- fused prep: x-cvt (8192 blk) | w-cvt (4096 blk) | mask flags (512) --
__global__ void prep_k(const float* __restrict__ x, const float* __restrict__ Wq,
                       const float* __restrict__ Wk, const float* __restrict__ Wv,
                       const float* __restrict__ Wo, const int* __restrict__ mask,
                       _Float16* __restrict__ xh, _Float16* __restrict__ Wqkv,
                       _Float16* __restrict__ Woh, unsigned char* __restrict__ flags) {
  int b = blockIdx.x;
  if (b < 8192) {                       // x: fp32 -> f16, 2097152 float4s
    int i = b * 256 + threadIdx.x;
    float4 v = ((const float4*)x)[i];
    half4v h;
    h.x = (_Float16)v.x; h.y = (_Float16)v.y; h.z = (_Float16)v.z; h.w = (_Float16)v.w;
    ((half4v*)xh)[i] = h;
  } else if (b < 12288) {               // weights: pack Wq|Wk|Wv -> Wqkv, Wo -> Woh
    int i = (b - 8192) * 256 + threadIdx.x;
    int which = i >> 18;
    int local = i & 262143;
    const float* src = which == 0 ? Wq : which == 1 ? Wk : which == 2 ? Wv : Wo;
    float4 v = ((const float4*)src)[local];
    half4v h;
    h.x = (_Float16)v.x; h.y = (_Float16)v.y; h.z = (_Float16)v.z; h.w = (_Float16)v.w;
    _Float16* dst = which < 3 ? Wqkv + (size_t)which * 1048576 : Woh;
    ((half4v*)dst)[local] = h;
  } else {                              // mask tile flags: 512 blocks, 128x64 tiles
    int bb = b - 12288;
    int qt = bb & 15, kt = bb >> 4;
    __shared__ int allv;
    if (threadIdx.x == 0) allv = 1;
    __syncthreads();
    int ok = 1;
    for (int idx = threadIdx.x; idx < 128 * 64; idx += 256) {
      int qr = qt * 128 + (idx >> 6);
      int kc = kt * 64 + (idx & 63);
      ok &= (mask[(size_t)qr * 2048 + kc] != 0);
    }
    if (!ok) atomicAnd(&allv, 0);
    __syncthreads();
    if (threadIdx.x == 0) flags[qt * 32 + kt] = (unsigned char)allv;
  }
}

// stage one 128x32 f16 tile (8KB) from src row-major [.,1024] into DST
#define STAGE_TILE(DST, SRC, base0, kk0)                                         \
  _Pragma("unroll")                                                              \
  for (int cc = 0; cc < 2; ++cc) {                                               \
    int oo = w * 2048 + cc * 1024 + l * 16;                                      \
    int row_ = oo >> 6;                                                          \
    int kb_ = (oo & 63) >> 1;                                                    \
    gld_lds16(SRC + (size_t)((base0) + row_) * 1024 + (kk0) + kb_,               \
              (char*)&DST[0][0] + w * 2048 + cc * 1024);                         \
  }

// ds_read fragments + 16 MFMA on buffer BUFI
#define GEMM_COMPUTE(BUFI)                                                       \
  {                                                                              \
    half8 af[4], bf[4];                                                          \
    _Pragma("unroll")                                                            \
    for (int m = 0; m < 4; ++m) af[m] = *(const half8*)&Alds[BUFI][wm * 64 + m * 16 + lm][lg * 8]; \
    _Pragma("unroll")                                                            \
    for (int n = 0; n < 4; ++n) bf[n] = *(const half8*)&Blds[BUFI][wn * 64 + n * 16 + lm][lg * 8]; \
    __builtin_amdgcn_s_setprio(1);                                               \
    _Pragma("unroll")                                                            \
    for (int m = 0; m < 4; ++m)                                                  \
      _Pragma("unroll")                                                          \
      for (int n = 0; n < 4; ++n)                                                \
        acc[m][n] = __builtin_amdgcn_mfma_f32_16x16x32_f16(af[m], bf[n], acc[m][n], 0, 0, 0); \
    __builtin_amdgcn_s_setprio(0);                                               \
  }

// ---------------- fused QKV GEMM: y[8192,3072] = x @ Wqkv^T + bias (T4 schedule) ------
__global__ __launch_bounds__(256) void gemm_qkv(const _Float16* __restrict__ A,
                                                const _Float16* __restrict__ B,
                                                const float* __restrict__ bq,
                                                const float* __restrict__ bk,
                                                const float* __restrict__ bv,
                                                _Float16* __restrict__ Qw,
                                                _Float16* __restrict__ Kw,
                                                _Float16* __restrict__ Vtt,
                                                float qscale) {
  __shared__ _Float16 Alds[2][128][32];
  __shared__ _Float16 Blds[2][128][32];
  int tid = threadIdx.x, w = tid >> 6, l = tid & 63;
  int lm = l & 15, lg = l >> 4;
  int wm = w >> 1, wn = w & 1;
  int wg = blockIdx.y * 24 + blockIdx.x;   // 1536 blocks
  int xcd = wg & 7, j = wg >> 3;           // j in 0..191
  int panel = j >> 6, rem = j & 63;        // 3 n-panels of 8m x 8n
  int m0 = (xcd * 8 + (rem >> 3)) * 128;
  int n0 = (panel * 8 + (rem & 7)) * 128;
  f32x4 acc[4][4] = {};
  STAGE_TILE(Alds[0], A, m0, 0);
  STAGE_TILE(Blds[0], B, n0, 0);
  int buf = 0;
  for (int k0 = 0; k0 < 992; k0 += 32) {
    STAGE_TILE(Alds[buf ^ 1], A, m0, k0 + 32);
    STAGE_TILE(Blds[buf ^ 1], B, n0, k0 + 32);
    asm volatile("s_waitcnt vmcnt(4)" ::: "memory");
    __builtin_amdgcn_s_barrier();
    __builtin_amdgcn_sched_barrier(0);
    GEMM_COMPUTE(buf);
    __builtin_amdgcn_sched_barrier(0);
    __builtin_amdgcn_s_barrier();
    buf ^= 1;
  }
  asm volatile("s_waitcnt vmcnt(0)" ::: "memory");
  __builtin_amdgcn_s_barrier();
  __builtin_amdgcn_sched_barrier(0);
  GEMM_COMPUTE(buf);
  int which = n0 >> 10;                       // 0:Q 1:K 2:V (uniform per block)
  float osc = which == 0 ? qscale : 1.0f;
  const float* bias = which == 0 ? bq : which == 1 ? bk : bv;
  int cq0 = n0 & 1023;
  float bs[4];
#pragma unroll
  for (int n = 0; n < 4; ++n) bs[n] = bias[cq0 + wn * 64 + n * 16 + lm];
#pragma unroll
  for (int m = 0; m < 4; ++m) {
#pragma unroll
    for (int n = 0; n < 4; ++n) {
      int cq = cq0 + wn * 64 + n * 16 + lm;
      int hh = cq >> 6, d = cq & 63;
#pragma unroll
      for (int j2 = 0; j2 < 4; ++j2) {
        int rowg = m0 + wm * 64 + m * 16 + lg * 4 + j2;
        int b = rowg >> 11, s = rowg & 2047;
        float v = (acc[m][n][j2] + bs[n]) * osc;
        if (which == 2) {
          Vtt[((size_t)(b * 16 + hh) * 64 + d) * 2048 + s] = (_Float16)v;
        } else {
          _Float16* dst = which == 0 ? Qw : Kw;
          dst[((size_t)(b * 16 + hh) * 2048 + s) * 64 + d] = (_Float16)v;
        }
      }
    }
  }
}

// ---------------- output GEMM: y[8192,1024] = A @ Wo^T + bo (fp32 out), T4 schedule ---
__global__ __launch_bounds__(256) void gemm_o(const _Float16* __restrict__ A,
                                              const _Float16* __restrict__ B,
                                              const float* __restrict__ bias,
                                              float* __restrict__ dst) {
  __shared__ _Float16 Alds[2][128][32];
  __shared__ _Float16 Blds[2][128][32];
  int tid = threadIdx.x, w = tid >> 6, l = tid & 63;
  int lm = l & 15, lg = l >> 4;
  int wm = w >> 1, wn = w & 1;
  int wg = blockIdx.y * 8 + blockIdx.x;
  int xcd = wg & 7, j = wg >> 3;
  int m0 = (xcd * 8 + (j >> 3)) * 128, n0 = (j & 7) * 128;
  f32x4 acc[4][4] = {};
  STAGE_TILE(Alds[0], A, m0, 0);
  STAGE_TILE(Blds[0], B, n0, 0);
  int buf = 0;
  for (int k0 = 0; k0 < 992; k0 += 32) {
    STAGE_TILE(Alds[buf ^ 1], A, m0, k0 + 32);
    STAGE_TILE(Blds[buf ^ 1], B, n0, k0 + 32);
    asm volatile("s_waitcnt vmcnt(4)" ::: "memory");
    __builtin_amdgcn_s_barrier();
    __builtin_amdgcn_sched_barrier(0);
    GEMM_COMPUTE(buf);
    __builtin_amdgcn_sched_barrier(0);
    __builtin_amdgcn_s_barrier();
    buf ^= 1;
  }
  asm volatile("s_waitcnt vmcnt(0)" ::: "memory");
  __builtin_amdgcn_s_barrier();
  __builtin_amdgcn_sched_barrier(0);
  GEMM_COMPUTE(buf);
  float bs[4];
#pragma unroll
  for (int n = 0; n < 4; ++n) bs[n] = bias[n0 + wn * 64 + n * 16 + lm];
#pragma unroll
  for (int m = 0; m < 4; ++m)
#pragma unroll
    for (int n = 0; n < 4; ++n) {
      int colg = n0 + wn * 64 + n * 16 + lm;
#pragma unroll
      for (int j2 = 0; j2 < 4; ++j2) {
        int rowg = m0 + wm * 64 + m * 16 + lg * 4 + j2;
        dst[(size_t)rowg * 1024 + colg] = acc[m][n][j2] + bs[n];
      }
    }
}

// ---------------- flash attention (FROZEN from round 21 best) ----------------
__global__ __launch_bounds__(256) void attn_k(const _Float16* __restrict__ Q,
                                              const _Float16* __restrict__ K,
                                              const _Float16* __restrict__ Vt,
                                              const unsigned char* __restrict__ flags,
                                              const int* __restrict__ mask,
                                              _Float16* __restrict__ out) {
  __shared__ __align__(16) char lds[2][16384];  // per buf: K tile 8KB, V tile 8KB
  int bh = blockIdx.x, qt = blockIdx.y;
  int tid = threadIdx.x, w = tid >> 6, l = tid & 63;
  int c = l & 31, h = l >> 5;
  const size_t hb = (size_t)bh * (2048 * 64);
  int q0 = qt * 128 + w * 32;
  const _Float16* Kb = K + hb;
  const _Float16* Vb = Vt + hb;
  const unsigned char* fl = flags + qt * 32;

  int sr = (l >> 3), scb = (l & 7) * 16;

  half8 qf[4];
#pragma unroll
  for (int ds = 0; ds < 4; ++ds)
    qf[ds] = *(const half8*)&Q[hb + (size_t)(q0 + c) * 64 + ds * 16 + h * 8];

  f32x16 oaccT[2] = {};
  float mrun = -1e30f;
  float lrun = 0.f;

#pragma unroll
  for (int i = 0; i < 2; ++i) {
    int r = w * 16 + i * 8 + sr;
    int dk = (scb ^ ((r & 7) << 4)) >> 1;
    gld_lds16(Kb + (size_t)r * 64 + dk, &lds[0][(w * 16 + i * 8) * 128]);
    gld_lds16(Vb + (size_t)r * 2048 + dk, &lds[0][8192 + (w * 16 + i * 8) * 128]);
  }
  __syncthreads();
  int buf = 0;

  for (int t = 0; t < 32; ++t) {
    if (t < 31) {
#pragma unroll
      for (int i = 0; i < 2; ++i) {
        int r = w * 16 + i * 8 + sr;
        int dk = (scb ^ ((r & 7) << 4)) >> 1;
        gld_lds16(Kb + (size_t)((t + 1) * 64 + r) * 64 + dk,
                  &lds[buf ^ 1][(w * 16 + i * 8) * 128]);
        gld_lds16(Vb + (size_t)r * 2048 + (t + 1) * 64 + dk,
                  &lds[buf ^ 1][8192 + (w * 16 + i * 8) * 128]);
      }
    }
    int flg = fl[t];
    f32x16 sT[2];
    f32x16 z = {};
    __builtin_amdgcn_s_setprio(1);
#pragma unroll
    for (int n = 0; n < 2; ++n) {
      int kr = n * 32 + c;
#pragma unroll
      for (int ds = 0; ds < 4; ++ds) {
        half8 kf = *(const half8*)&lds[buf][kr * 128 + ((ds * 32 + h * 16) ^ ((kr & 7) << 4))];
        sT[n] = ds == 0 ? __builtin_amdgcn_mfma_f32_32x32x16_f16(kf, qf[0], z, 0, 0, 0)
                        : __builtin_amdgcn_mfma_f32_32x32x16_f16(kf, qf[ds], sT[n], 0, 0, 0);
      }
    }
    __builtin_amdgcn_s_setprio(0);
    if (!flg) {
#pragma unroll
      for (int n = 0; n < 2; ++n)
#pragma unroll
        for (int r = 0; r < 16; ++r) {
          int kc = t * 64 + n * 32 + (r & 3) + 8 * (r >> 2) + 4 * h;
          if (mask[(size_t)(q0 + c) * 2048 + kc] == 0) sT[n][r] = -1e30f;
        }
    }
    // ---- row max: v_max3-friendly nesting (T17), then permlane cross-half ----
    float m8[8];
#pragma unroll
    for (int r = 0; r < 8; ++r)
      m8[r] = fmaxf(fmaxf(fmaxf(sT[0][r], sT[0][r + 8]), sT[1][r]), sT[1][r + 8]);
    float pmax = fmaxf(fmaxf(fmaxf(m8[0], m8[1]), m8[2]),
                       fmaxf(fmaxf(fmaxf(m8[3], m8[4]), m8[5]), fmaxf(m8[6], m8[7])));
    {
      uint2v pr = __builtin_amdgcn_permlane32_swap(__float_as_uint(pmax), __float_as_uint(pmax),
                                                   false, false);
      pmax = fmaxf(__uint_as_float(pr[0]), __uint_as_float(pr[1]));
    }
    if (!__all(pmax - mrun <= 8.f)) {
      float mnew = fmaxf(mrun, pmax);
      float alpha = fexp2(mrun - mnew);
#pragma unroll
      for (int dh = 0; dh < 2; ++dh)
#pragma unroll
        for (int r = 0; r < 16; ++r) oaccT[dh][r] *= alpha;
      lrun *= alpha;
      mrun = mnew;
    }
    unsigned pk_[2][8];
    float psum = 0.f;
#pragma unroll
    for (int n = 0; n < 2; ++n)
#pragma unroll
      for (int g = 0; g < 4; ++g) {
        float p0 = fexp2(sT[n][4 * g + 0] - mrun);
        float p1 = fexp2(sT[n][4 * g + 1] - mrun);
        float p2 = fexp2(sT[n][4 * g + 2] - mrun);
        float p3 = fexp2(sT[n][4 * g + 3] - mrun);
        psum += (p0 + p1) + (p2 + p3);
        pk_[n][2 * g] = pku(p0, p1);
        pk_[n][2 * g + 1] = pku(p2, p3);
      }
    lrun += psum;
    __builtin_amdgcn_s_setprio(1);
#pragma unroll
    for (int n = 0; n < 2; ++n)
#pragma unroll
      for (int sp = 0; sp < 2; ++sp) {
        // T12: one permlane32_swap yields both output words
        uint2v r0 = __builtin_amdgcn_permlane32_swap(pk_[n][4 * sp + 0], pk_[n][4 * sp + 2], false, false);
        uint2v r1 = __builtin_amdgcn_permlane32_swap(pk_[n][4 * sp + 1], pk_[n][4 * sp + 3], false, false);
        union { unsigned u[4]; half8 v; } pb;
        pb.u[0] = r0[0];
        pb.u[1] = r1[0];
        pb.u[2] = r0[1];
        pb.u[3] = r1[1];
        int s = n * 2 + sp;
#pragma unroll
        for (int dh = 0; dh < 2; ++dh) {
          int vr = dh * 32 + c;
          half8 vfr = *(const half8*)&lds[buf][8192 + vr * 128 + ((s * 32 + h * 16) ^ ((vr & 7) << 4))];
          oaccT[dh] = __builtin_amdgcn_mfma_f32_32x32x16_f16(vfr, pb.v, oaccT[dh], 0, 0, 0);
        }
      }
    __builtin_amdgcn_s_setprio(0);
    __syncthreads();
    buf ^= 1;
  }
  char* Pl = &lds[0][w * 4096];
  int bb = bh >> 4, hh = bh & 15;
  float lsum = lrun + __shfl_xor(lrun, 32, 64);
  float rinv = 1.0f / lsum;
#pragma unroll
  for (int dh = 0; dh < 2; ++dh)
#pragma unroll
    for (int g = 0; g < 4; ++g) {
      int dbase = dh * 32 + 8 * g + 4 * h;
      int byte = c * 128 + ((dbase * 2) ^ ((c & 7) << 4));
      *(half4v*)(&Pl[byte]) = pk4(oaccT[dh][4 * g + 0] * rinv, oaccT[dh][4 * g + 1] * rinv,
                                  oaccT[dh][4 * g + 2] * rinv, oaccT[dh][4 * g + 3] * rinv);
    }
#pragma unroll
  for (int r = 0; r < 4; ++r) {
    int o = r * 1024 + l * 16;
    int row = o >> 7;
    int pb_ = o & 127;
    int d2 = pb_ ^ ((row & 7) << 4);
    half8 v = *(const half8*)&Pl[row * 128 + pb_];
    *(half8*)&out[((size_t)(bb * 2048 + q0 + row)) * 1024 + hh * 64 + (d2 >> 1)] = v;
  }
}

extern "C" void kernel_launch(void* const* d_in, const int* in_sizes, int n_in,
                              void* d_out, int out_size, void* d_ws, size_t ws_size,
                              hipStream_t stream) {
  const float* x = (const float*)d_in[0];
  const int* mask = (const int*)d_in[1];
  const float* Wq = (const float*)d_in[2];
  const float* bq = (const float*)d_in[3];
  const float* Wk = (const float*)d_in[4];
  const float* bk = (const float*)d_in[5];
  const float* Wv = (const float*)d_in[6];
  const float* bv = (const float*)d_in[7];
  const float* Wo = (const float*)d_in[8];
  const float* bo = (const float*)d_in[9];

  char* ws = (char*)d_ws;
  _Float16* xh = (_Float16*)(ws);                       // 16 MB, later reused as attn out
  _Float16* Wqkvh = (_Float16*)(ws + (16ull << 20));    // 6 MB packed [3072][1024]
  _Float16* Woh = (_Float16*)(ws + (22ull << 20));      // 2 MB
  _Float16* Vt = (_Float16*)(ws + (24ull << 20));       // 16 MB
  unsigned char* flags = (unsigned char*)(ws + (40ull << 20));  // 512 B
  // Q and K scratch live inside d_out (32 MB fp32), fully overwritten by final GEMM
  _Float16* Qw = (_Float16*)d_out;
  _Float16* Kw = (_Float16*)((char*)d_out + (16ull << 20));
  _Float16* Ah = xh;  // attention output reuses x-f16 region

  const float QSCALE = 0.125f * 1.4426950408889634f;  // 1/sqrt(64) * log2(e)

  prep_k<<<12800, 256, 0, stream>>>(x, Wq, Wk, Wv, Wo, mask, xh, Wqkvh, Woh, flags);
  gemm_qkv<<<dim3(24, 64), 256, 0, stream>>>(xh, Wqkvh, bq, bk, bv, Qw, Kw, Vt, QSCALE);
  attn_k<<<dim3(64, 16), 256, 0, stream>>>(Qw, Kw, Vt, flags, mask, Ah);
  gemm_o<<<dim3(8, 64), 256, 0, stream>>>(Ah, Woh, bo, (float*)d_out);
}